// Round 6
// baseline (554.493 us; speedup 1.0000x reference)
//
#include <hip/hip_runtime.h>
#include <stdint.h>

// Problem constants (reference: N=8192, IN_DIM=512, LDIM=256)
#define NN 8192
#define KDIM 512
#define LDIM 256

typedef short bf16x8 __attribute__((ext_vector_type(8)));
typedef short short8 __attribute__((ext_vector_type(8)));
typedef float f32x4 __attribute__((ext_vector_type(4)));
typedef unsigned short u16x4 __attribute__((ext_vector_type(4)));

// fp32 -> bf16 with round-to-nearest-even
__device__ __forceinline__ unsigned short f2bf(float f) {
  unsigned int u = __float_as_uint(f);
  u = (u + 0x7fffu + ((u >> 16) & 1u)) >> 16;
  return (unsigned short)u;
}
__device__ __forceinline__ float bf2f(unsigned short s) {
  return __uint_as_float(((unsigned int)s) << 16);
}

// async global->LDS, 16B per lane; LDS dest = wave-uniform base + lane*16
__device__ __forceinline__ void async_ld16(const unsigned short* g, void* l) {
  __builtin_amdgcn_global_load_lds(
      (const __attribute__((address_space(1))) unsigned int*)g,
      (__attribute__((address_space(3))) unsigned int*)l, 16, 0, 0);
}

// Cast proj_w [256x512] to bf16 (x is now consumed fp32 by gemm1_norm).
__global__ __launch_bounds__(256) void cast_pw_kernel(
    const float* __restrict__ pw, unsigned short* __restrict__ pwb) {
  const int i = blockIdx.x * 256 + threadIdx.x;  // float4 index, 32768 total
  float4 w = ((const float4*)pw)[i];
  u16x4 ow;
  ow[0] = (short)f2bf(w.x); ow[1] = (short)f2bf(w.y);
  ow[2] = (short)f2bf(w.z); ow[3] = (short)f2bf(w.w);
  ((u16x4*)pwb)[i] = ow;
}

// Fused cast(x) + GEMM1 + row-normalize:
//   x_hat = bf16(x) @ pwb^T (M=8192, N=256, K=512), per-row L2 norm,
//   emit Ab = bf16(xn*w), Bb = bf16(xn). x read ONCE as fp32; xb and xhat
//   never touch global memory.
// One block per 32 rows (256 blocks). Upfront: convert the block's 32x512
// x-rows to LDS bf16 (stride 520: rows land 4 banks apart -> 2-way free).
// K-loop stages only the pwb tile (16 KB/iter via global_load_lds).
__global__ __launch_bounds__(256) void gemm1_norm_kernel(
    const float* __restrict__ x,
    const unsigned short* __restrict__ pwb,
    const float* __restrict__ w,
    unsigned short* __restrict__ Ab, unsigned short* __restrict__ Bb) {
  __shared__ alignas(16) unsigned short Axl[32 * 520];  // 33.3 KB bf16 x-tile
  __shared__ alignas(16) unsigned short Bs[256 * 32];   // 16 KB
  __shared__ float nrm[32][5];  // [row][4 wave partials + inv]
  __shared__ float wS[LDIM];
  __shared__ alignas(16) unsigned short xnS[32][264];   // bf16 xn tile (pad 8)
  __shared__ alignas(16) unsigned short anS[32][264];   // bf16 xn*w tile

  const int tid = threadIdx.x;
  const int wave = tid >> 6;
  const int lane = tid & 63;
  const int quad = lane >> 4;
  const int l16 = lane & 15;
  const size_t row0 = (size_t)blockIdx.x * 32;

  if (tid < LDIM) wS[tid] = w[tid];

  // upfront: 32x512 fp32 -> bf16 LDS (16 rounds of float4/thread, coalesced)
  {
    const float4* xr = (const float4*)(x + row0 * KDIM);
#pragma unroll
    for (int rnd = 0; rnd < 16; ++rnd) {
      const int idx = rnd * 256 + tid;  // float4 index in the 32x512 tile
      float4 v = xr[idx];
      u16x4 o;
      o[0] = (short)f2bf(v.x); o[1] = (short)f2bf(v.y);
      o[2] = (short)f2bf(v.z); o[3] = (short)f2bf(v.w);
      const int e = idx * 4;
      *(u16x4*)&Axl[(e >> 9) * 520 + (e & 511)] = o;
    }
  }
  __syncthreads();

  f32x4 acc[2][4];
#pragma unroll
  for (int i = 0; i < 2; ++i)
#pragma unroll
    for (int j = 0; j < 4; ++j) acc[i][j] = (f32x4)(0.0f);

  // K-loop: stage B tile [256 rows][32 k]: chunk c=(wave*4+j)*64+lane
  //   -> row=c>>2, koff=(c&3)*8; A-fragments read from Axl (no restage).
  for (int k0 = 0; k0 < KDIM; k0 += 32) {
#pragma unroll
    for (int j = 0; j < 4; ++j) {
      const int c = (wave * 4 + j) * 64 + lane;
      async_ld16(pwb + (size_t)(c >> 2) * KDIM + (c & 3) * 8 + k0,
                 (char*)Bs + (wave * 4 + j) * 1024);
    }
    __syncthreads();  // drain staging
    bf16x8 av[2], bv[4];
#pragma unroll
    for (int mt = 0; mt < 2; ++mt)
      av[mt] = *(const bf16x8*)(Axl + (mt * 16 + l16) * 520 + k0 + quad * 8);
#pragma unroll
    for (int nt = 0; nt < 4; ++nt)
      bv[nt] = *(const bf16x8*)(Bs + (wave * 64 + nt * 16 + l16) * 32 + quad * 8);
#pragma unroll
    for (int mt = 0; mt < 2; ++mt)
#pragma unroll
      for (int nt = 0; nt < 4; ++nt)
        acc[mt][nt] = __builtin_amdgcn_mfma_f32_16x16x32_bf16(
            av[mt], bv[nt], acc[mt][nt], 0, 0, 0);
    __syncthreads();  // Bs reads done before restage
  }

  // per-(row,wave) sum of squares: lane holds rows 16*mt+quad*4+r,
  // cols l16+16*nt+64*wave. Reduce over l16 (16 lanes, same quad).
#pragma unroll
  for (int mt = 0; mt < 2; ++mt)
#pragma unroll
    for (int r = 0; r < 4; ++r) {
      float s = 0.0f;
#pragma unroll
      for (int nt = 0; nt < 4; ++nt) s += acc[mt][nt][r] * acc[mt][nt][r];
      s += __shfl_xor(s, 1);
      s += __shfl_xor(s, 2);
      s += __shfl_xor(s, 4);
      s += __shfl_xor(s, 8);
      if (l16 == 0) nrm[mt * 16 + quad * 4 + r][wave] = s;
    }
  __syncthreads();
  if (tid < 32)
    nrm[tid][4] = rsqrtf(nrm[tid][0] + nrm[tid][1] + nrm[tid][2] + nrm[tid][3]);
  __syncthreads();

  // scale from full-precision accumulators; stage bf16 tiles in LDS
#pragma unroll
  for (int mt = 0; mt < 2; ++mt)
#pragma unroll
    for (int r = 0; r < 4; ++r) {
      const int row = mt * 16 + quad * 4 + r;
      const float inv = nrm[row][4];
#pragma unroll
      for (int nt = 0; nt < 4; ++nt) {
        const int col = wave * 64 + nt * 16 + l16;
        const float xn = acc[mt][nt][r] * inv;
        xnS[row][col] = f2bf(xn);
        anS[row][col] = f2bf(xn * wS[col]);
      }
    }
  __syncthreads();

  // repack-store: thread t -> row t>>3, cols (t&7)*32..+32 (4x 16B each)
  {
    const int row = tid >> 3;
    const int cb = (tid & 7) * 32;
    unsigned short* bdst = Bb + (row0 + row) * LDIM + cb;
    unsigned short* adst = Ab + (row0 + row) * LDIM + cb;
#pragma unroll
    for (int q = 0; q < 4; ++q) {
      ((short8*)bdst)[q] = *(const short8*)&xnS[row][cb + q * 8];
      ((short8*)adst)[q] = *(const short8*)&anS[row][cb + q * 8];
    }
  }
}

// GEMM2: D = A * B^T (A=xn*w, B=xn, [8192,256] bf16 K-major), then
// t = adj*exp(-D) with rowsums. Round-0 proven K-loop (serial
// global_load_lds staging, 2 barriers/K-step) + XCD swizzle. Epilogue:
// slab-LDS-transpose with HALVED slabs (16x132, 8 phases) so total LDS
// drops 33.9 -> 25.3 KB => 5-6 blocks/CU (was 4). Rationale: r4/r5 showed
// intra-block latency tricks are neutral -- inter-block TLP is the hiding
// mechanism, so resident-block count is the lever.
// MODE 1: t -> bf16 T + rowsum atomics.   MODE 2: t -> fp32 C + rowsums.
template <int K, int MODE>
__global__ __launch_bounds__(256, 5) void gemm_bt(
    const unsigned short* __restrict__ A,
    const unsigned short* __restrict__ B,
    float* __restrict__ C,
    unsigned short* __restrict__ T,
    const float* __restrict__ adj,
    float* __restrict__ rowsum) {
  __shared__ unsigned short As[128 * 32];   // 8 KB
  __shared__ unsigned short Bs[128 * 32];   // 8 KB
  __shared__ float rs[128];                 // 0.5 KB
  __shared__ float trans[16 * 132];         // 8.25 KB half-slab transpose

  const int tid = threadIdx.x;
  const int wave = tid >> 6;
  const int lane = tid & 63;
  const int quad = lane >> 4;
  const int l16 = lane & 15;
  const int wm = wave >> 1;
  const int wn = wave & 1;

  // XCD swizzle: lin -> (xcd band of 8 consecutive y-tiles, x sweeps fastest)
  const int lin = blockIdx.y * 64 + blockIdx.x;
  const int swz = (lin & 7) * 512 + (lin >> 3);
  const size_t row0 = (size_t)(swz >> 6) * 128;
  const size_t col0 = (size_t)(swz & 63) * 128;

  // staging map: chunk c = wave*128 + lane covers LDS bytes [c*16, c*16+16)
  // tile layout [128 rows][32 k] bf16 => row m = c>>2, k offset = (c&3)*8
  const int c0 = wave * 128 + lane;
  const int mA = c0 >> 2;
  const int kA = (c0 & 3) * 8;
  const unsigned short* Ag = A + (row0 + mA) * (size_t)K + kA;
  const unsigned short* Bg = B + (col0 + mA) * (size_t)K + kA;
  char* AsB = (char*)As;
  char* BsB = (char*)Bs;
  unsigned short* dA0 = (unsigned short*)(AsB + wave * 2048);
  unsigned short* dA1 = (unsigned short*)(AsB + wave * 2048 + 1024);
  unsigned short* dB0 = (unsigned short*)(BsB + wave * 2048);
  unsigned short* dB1 = (unsigned short*)(BsB + wave * 2048 + 1024);

  f32x4 acc[4][4];
#pragma unroll
  for (int i = 0; i < 4; ++i)
#pragma unroll
    for (int j = 0; j < 4; ++j) acc[i][j] = (f32x4)(0.0f);

  for (int k0 = 0; k0 < K; k0 += 32) {
    async_ld16(Ag + k0, dA0);
    async_ld16(Ag + 16 * (size_t)K + k0, dA1);  // row m+16, same k offset
    async_ld16(Bg + k0, dB0);
    async_ld16(Bg + 16 * (size_t)K + k0, dB1);
    __syncthreads();  // drains vmcnt: staging complete

    bf16x8 av[4], bv[4];
#pragma unroll
    for (int mt = 0; mt < 4; ++mt)
      av[mt] = *(const bf16x8*)(AsB + (wm * 64 + mt * 16 + l16) * 64 + quad * 16);
#pragma unroll
    for (int nt = 0; nt < 4; ++nt)
      bv[nt] = *(const bf16x8*)(BsB + (wn * 64 + nt * 16 + l16) * 64 + quad * 16);
#pragma unroll
    for (int mt = 0; mt < 4; ++mt)
#pragma unroll
      for (int nt = 0; nt < 4; ++nt)
        acc[mt][nt] = __builtin_amdgcn_mfma_f32_16x16x32_bf16(av[mt], bv[nt], acc[mt][nt], 0, 0, 0);
    __syncthreads();  // all waves done reading LDS before next stage
  }

  // 8 phases: (mt, wm-half wh) -> 16x128 slab. Writers: the 2 waves with
  // wm==wh (16 f32/thread, same as before; other waves idle through the
  // write). Consumers: all 256 threads, 16 threads/row x 8 cols.
  const int sr = tid >> 4;   // 0..15: slab row this thread consumes
  const int cb = tid & 15;   // 16 threads/row, 8 cols each
  const int coff = cb * 8;
#pragma unroll
  for (int mt = 0; mt < 4; ++mt) {
#pragma unroll
    for (int wh = 0; wh < 2; ++wh) {
      __syncthreads();  // prior phase's reads done before overwrite
      if (wm == wh) {
#pragma unroll
        for (int nt = 0; nt < 4; ++nt)
#pragma unroll
          for (int r = 0; r < 4; ++r)
            trans[(quad * 4 + r) * 132 + wn * 64 + nt * 16 + l16] =
                acc[mt][nt][r];
      }
      __syncthreads();
      const size_t gr = row0 + (size_t)wh * 64 + mt * 16 + sr;
      const float* arow = adj + gr * NN + col0 + coff;
      float av8[8];
#pragma unroll
      for (int q = 0; q < 2; ++q) {
        float4 a4 = ((const float4*)arow)[q];
        av8[q * 4 + 0] = a4.x;
        av8[q * 4 + 1] = a4.y;
        av8[q * 4 + 2] = a4.z;
        av8[q * 4 + 3] = a4.w;
      }
      const float* drow = &trans[sr * 132 + coff];
      float part = 0.0f;
      if constexpr (MODE == 1) {
        short8 p0;
#pragma unroll
        for (int j = 0; j < 8; ++j) {
          float tv = av8[j] * __expf(-drow[j]);
          unsigned short us = f2bf(tv);
          part += bf2f(us);  // rowsum of the *rounded* t: self-consistent
          p0[j] = (short)us;
        }
        *(short8*)(T + gr * NN + col0 + coff) = p0;
      } else {
        float4 o[2];
#pragma unroll
        for (int j = 0; j < 8; ++j) {
          float tv = av8[j] * __expf(-drow[j]);
          part += tv;
          ((float*)o)[j] = tv;
        }
        float4* crow = (float4*)(C + gr * NN + col0 + coff);
        crow[0] = o[0];
        crow[1] = o[1];
      }
      // reduce the 16 threads sharing this row (lane group (sr&3)*16+cb)
      part += __shfl_xor(part, 1);
      part += __shfl_xor(part, 2);
      part += __shfl_xor(part, 4);
      part += __shfl_xor(part, 8);
      if (cb == 0) rs[wh * 64 + mt * 16 + sr] = part;  // unique owner
    }
  }
  __syncthreads();
  if (tid < 128) atomicAdd(&rowsum[row0 + tid], rs[tid]);
}

// out = bf16(t) * (1/rowsum[row]) + 1e-10; read ushort8, write 2x float4
// (round-0 proven variant)
__global__ __launch_bounds__(256) void scale_bf16_kernel(
    const unsigned short* __restrict__ T, const float* __restrict__ rowsum,
    float* __restrict__ out) {
  const size_t i = (size_t)blockIdx.x * 256 + threadIdx.x;  // short8 index
  const int row = (int)(i >> 10);  // 1024 short8 per row
  short8 tv = ((const short8*)T)[i];
  const float inv = 1.0f / rowsum[row];
  float4 o0, o1;
  o0.x = bf2f((unsigned short)tv[0]) * inv + 1e-10f;
  o0.y = bf2f((unsigned short)tv[1]) * inv + 1e-10f;
  o0.z = bf2f((unsigned short)tv[2]) * inv + 1e-10f;
  o0.w = bf2f((unsigned short)tv[3]) * inv + 1e-10f;
  o1.x = bf2f((unsigned short)tv[4]) * inv + 1e-10f;
  o1.y = bf2f((unsigned short)tv[5]) * inv + 1e-10f;
  o1.z = bf2f((unsigned short)tv[6]) * inv + 1e-10f;
  o1.w = bf2f((unsigned short)tv[7]) * inv + 1e-10f;
  ((float4*)out)[i * 2] = o0;
  ((float4*)out)[i * 2 + 1] = o1;
}

// Fallback: in-place out = t / rowsum[row] + 1e-10 (t fp32 already in out)
__global__ __launch_bounds__(256) void scale_f32_kernel(
    float* __restrict__ t, const float* __restrict__ rowsum) {
  const size_t i = (size_t)blockIdx.x * 256 + threadIdx.x;
  const int row = (int)(i >> 11);
  float4 v = ((float4*)t)[i];
  const float inv = 1.0f / rowsum[row];
  v.x = v.x * inv + 1e-10f;
  v.y = v.y * inv + 1e-10f;
  v.z = v.z * inv + 1e-10f;
  v.w = v.w * inv + 1e-10f;
  ((float4*)t)[i] = v;
}

extern "C" void kernel_launch(void* const* d_in, const int* in_sizes, int n_in,
                              void* d_out, int out_size, void* d_ws, size_t ws_size,
                              hipStream_t stream) {
  (void)in_sizes; (void)n_in; (void)out_size;
  const float* x   = (const float*)d_in[0];  // [8192,512]
  const float* adj = (const float*)d_in[1];  // [8192,8192]
  const float* pw  = (const float*)d_in[2];  // [256,512]
  const float* lw  = (const float*)d_in[3];  // [256]
  float* out = (float*)d_out;                // [8192,8192]
  char* ws = (char*)d_ws;

  // ws layout (bytes) -- unchanged offsets (xb/xhat holes now unused)
  unsigned short* pwb  = (unsigned short*)(ws + 8388608);    // 256 KB
  unsigned short* Ab   = (unsigned short*)(ws + 17039360);   // 4 MB
  unsigned short* Bb   = (unsigned short*)(ws + 21233664);   // 4 MB
  float*          rsum = (float*)(ws + 25427968);            // 32 KB
  unsigned short* Tbuf = (unsigned short*)(ws + 25460736);   // 128 MB (if fits)
  const bool big_ws = ws_size >= 25460736ull + (size_t)NN * NN * 2ull;

  // 1) cast proj_w to bf16 (x consumed fp32 directly by the fused kernel)
  cast_pw_kernel<<<(LDIM * KDIM) / (256 * 4), 256, 0, stream>>>(pw, pwb);
  // 2+3) fused: cast x, x_hat = x @ proj_w^T, row-normalize, emit A,B (bf16)
  gemm1_norm_kernel<<<NN / 32, 256, 0, stream>>>(x, pwb, lw, Ab, Bb);
  // 4) t = adj * exp(-(A@B^T)), plus rowsums
  hipMemsetAsync(rsum, 0, NN * sizeof(float), stream);
  if (big_ws) {
    gemm_bt<LDIM, 1><<<dim3(64, 64), 256, 0, stream>>>(Ab, Bb, nullptr, Tbuf, adj, rsum);
    // 5) out = t / rowsum + eps
    scale_bf16_kernel<<<(NN / 8) * (NN / 256), 256, 0, stream>>>(Tbuf, rsum, out);
  } else {
    gemm_bt<LDIM, 2><<<dim3(64, 64), 256, 0, stream>>>(Ab, Bb, out, nullptr, adj, rsum);
    scale_f32_kernel<<<(NN / 4) * (NN / 256), 256, 0, stream>>>(out, rsum);
  }
}